// Round 1
// baseline (199.662 us; speedup 1.0000x reference)
//
#include <hip/hip_runtime.h>
#include <math.h>

#define B 8
#define C 3
#define H 1024
#define W 1024
#define L 1024
#define D 512
#define DH 128
#define NPIX (H * W)              // 1048576
#define NOISY_ELEMS (B * C * NPIX) // 25165824

struct BlurW { float w[21]; };

// ---------------- kernel 1: partial column sums of bottleneck_feat ----------
// grid: B*64 blocks, 256 threads. Each block sums 16 rows (L/64) of one batch.
__global__ void colsum_kernel(const float* __restrict__ feat, float* __restrict__ partial) {
    int blk = blockIdx.x;            // 0..511
    int b = blk >> 6, chunk = blk & 63;
    const float* base = feat + (size_t)b * (L * D) + (size_t)chunk * 16 * D;
    int t = threadIdx.x;             // 256
    float s0 = 0.f, s1 = 0.f;
    for (int l = 0; l < 16; ++l) {
        s0 += base[l * D + t];
        s1 += base[l * D + t + 256];
    }
    float* dst = partial + (size_t)blk * D;
    dst[t] = s0;
    dst[t + 256] = s1;
}

// ---------------- kernel 2: MLP head -> alpha/beta --------------------------
// grid: B blocks, 128 threads.
__global__ void head_kernel(const float* __restrict__ partial,
                            const float* __restrict__ W1, const float* __restrict__ b1,
                            const float* __restrict__ ln_g, const float* __restrict__ ln_b,
                            const float* __restrict__ W2, const float* __restrict__ b2,
                            float* __restrict__ ab, float* __restrict__ out_tail) {
    const int b = blockIdx.x;
    const int j = threadIdx.x;   // 0..127
    __shared__ float fm[D];
    __shared__ float red[DH];
    for (int d = j; d < D; d += DH) {
        float s = 0.f;
        const float* p = partial + (size_t)b * 64 * D + d;
        for (int c = 0; c < 64; ++c) s += p[c * D];
        fm[d] = s * (1.0f / (float)L);
    }
    __syncthreads();
    float h = b1[j];
    for (int d = 0; d < D; ++d) h = fmaf(fm[d], W1[d * DH + j], h);

    // mean
    red[j] = h; __syncthreads();
    for (int s = 64; s > 0; s >>= 1) { if (j < s) red[j] += red[j + s]; __syncthreads(); }
    float mu = red[0] * (1.f / (float)DH);
    __syncthreads();
    // var
    float hc = h - mu;
    red[j] = hc * hc; __syncthreads();
    for (int s = 64; s > 0; s >>= 1) { if (j < s) red[j] += red[j + s]; __syncthreads(); }
    float var = red[0] * (1.f / (float)DH);
    __syncthreads();

    float hn = hc * rsqrtf(var + 1e-5f) * ln_g[j] + ln_b[j];
    hn = fmaxf(hn, 0.f);

    red[j] = hn * W2[j * 2 + 0]; __syncthreads();
    for (int s = 64; s > 0; s >>= 1) { if (j < s) red[j] += red[j + s]; __syncthreads(); }
    float p0 = red[0];
    __syncthreads();
    red[j] = hn * W2[j * 2 + 1]; __syncthreads();
    for (int s = 64; s > 0; s >>= 1) { if (j < s) red[j] += red[j + s]; __syncthreads(); }
    float p1 = red[0];

    if (j == 0) {
        float a  = 0.00015f / (1.f + expf(-(p0 + b2[0])));
        float be = 0.00015f / (1.f + expf(-(p1 + b2[1])));
        ab[b] = a; ab[8 + b] = be;
        out_tail[b] = a; out_tail[8 + b] = be;
    }
}

// ---------------- kernel 3: horizontal 21-tap blur of mask ------------------
// grid: B*H blocks (one image row each), 256 threads.
__global__ void hblur_kernel(const float* __restrict__ mask, float* __restrict__ hmask,
                             BlurW kw) {
    int row = blockIdx.x;            // 0 .. B*H-1
    const float* src = mask + (size_t)row * W;
    __shared__ float srow[W + 24];   // data at [12 .. 12+W-1], zero halo 10 each side
    int t = threadIdx.x;             // 256
    if (t < 10) { srow[2 + t] = 0.f; srow[12 + W + t] = 0.f; }
    float4 v = ((const float4*)src)[t];
    ((float4*)(srow + 12))[t] = v;
    __syncthreads();
    float* dst = hmask + (size_t)row * W;
    #pragma unroll
    for (int i = 0; i < 4; ++i) {
        int x = t + 256 * i;
        float acc = 0.f;
        #pragma unroll
        for (int k = 0; k < 21; ++k) acc = fmaf(kw.w[k], srow[x + 2 + k], acc);
        dst[x] = acc;
    }
}

// ---------------- kernel 4: vertical blur + elementwise synth ---------------
// grid: B*H blocks (one output row each), 256 threads; float4 per thread.
__global__ void final_kernel(const float* __restrict__ x_bg, const float* __restrict__ noise,
                             const float* __restrict__ hmask, const float* __restrict__ ab,
                             float* __restrict__ out, BlurW kw) {
    int blk = blockIdx.x;
    int b = blk >> 10, h = blk & (H - 1);
    int t = threadIdx.x;             // 256, one float4 each
    const float4* hm4 = (const float4*)hmask;

    float4 ms = make_float4(0.f, 0.f, 0.f, 0.f);
    #pragma unroll
    for (int k = 0; k < 21; ++k) {
        int hy = h + k - 10;
        if (hy >= 0 && hy < H) {
            float4 v = hm4[((size_t)b * H + hy) * (W / 4) + t];
            float wk = kw.w[k];
            ms.x = fmaf(wk, v.x, ms.x);
            ms.y = fmaf(wk, v.y, ms.y);
            ms.z = fmaf(wk, v.z, ms.z);
            ms.w = fmaf(wk, v.w, ms.w);
        }
    }

    float alpha = ab[b], beta = ab[8 + b];
    const float4* x4 = (const float4*)x_bg;
    const float4* n4 = (const float4*)noise;
    float4* o4 = (float4*)out;

    #pragma unroll
    for (int c = 0; c < C; ++c) {
        size_t idx = (((size_t)(b * C + c) * H) + h) * (W / 4) + t;
        float4 x = x4[idx];
        float4 nz = n4[idx];
        float4 o;
        {
            float sg = sqrtf(fmaxf(fmaf(alpha, x.x, beta), 1e-7f));
            o.x = fmaf(1.5f * nz.x * sg, ms.x, x.x);
        }
        {
            float sg = sqrtf(fmaxf(fmaf(alpha, x.y, beta), 1e-7f));
            o.y = fmaf(1.5f * nz.y * sg, ms.y, x.y);
        }
        {
            float sg = sqrtf(fmaxf(fmaf(alpha, x.z, beta), 1e-7f));
            o.z = fmaf(1.5f * nz.z * sg, ms.z, x.z);
        }
        {
            float sg = sqrtf(fmaxf(fmaf(alpha, x.w, beta), 1e-7f));
            o.w = fmaf(1.5f * nz.w * sg, ms.w, x.w);
        }
        o4[idx] = o;
    }
}

extern "C" void kernel_launch(void* const* d_in, const int* in_sizes, int n_in,
                              void* d_out, int out_size, void* d_ws, size_t ws_size,
                              hipStream_t stream) {
    const float* x_bg = (const float*)d_in[0];
    const float* feat = (const float*)d_in[1];
    const float* mask = (const float*)d_in[2];
    const float* noise = (const float*)d_in[3];
    const float* W1 = (const float*)d_in[4];
    const float* b1 = (const float*)d_in[5];
    const float* ln_g = (const float*)d_in[6];
    const float* ln_b = (const float*)d_in[7];
    const float* W2 = (const float*)d_in[8];
    const float* b2 = (const float*)d_in[9];
    float* out = (float*)d_out;

    // ws layout (floats): [0, 32768) partial colsums (B*64*D) | [32768, 32784) ab | hmask
    float* ws_f = (float*)d_ws;
    float* partial = ws_f;                       // B*64*D = 262144 floats
    float* ab = ws_f + 262144;                   // 16 floats
    float* hmask = ws_f + 262144 + 64;           // B*H*W floats (16B-aligned offset)

    BlurW kw;
    {
        double g[21], s = 0.0;
        for (int i = 0; i < 21; ++i) { double x = (double)(i - 10); g[i] = exp(-x * x / 50.0); s += g[i]; }
        for (int i = 0; i < 21; ++i) kw.w[i] = (float)(g[i] / s);
    }

    colsum_kernel<<<B * 64, 256, 0, stream>>>(feat, partial);
    head_kernel<<<B, 128, 0, stream>>>(partial, W1, b1, ln_g, ln_b, W2, b2,
                                       ab, out + NOISY_ELEMS);
    hblur_kernel<<<B * H, 256, 0, stream>>>(mask, hmask, kw);
    final_kernel<<<B * H, 256, 0, stream>>>(x_bg, noise, hmask, ab, out, kw);
}

// Round 2
// 106.267 us; speedup vs baseline: 1.8789x; 1.8789x over previous
//
#include <hip/hip_runtime.h>
#include <math.h>

#define B 8
#define C 3
#define H 1024
#define W 1024
#define L 1024
#define D 512
#define DH 128
#define NPIX (H * W)               // 1048576
#define NOISY_ELEMS (B * C * NPIX) // 25165824
#define TH 16                      // rows per block in final kernel

typedef float vf4 __attribute__((ext_vector_type(4)));

struct BlurW { float w[21]; };

// ---------------- kernel 1: partial column sums of bottleneck_feat ----------
// grid: B*64 blocks, 256 threads. Each block sums 16 rows (L/64) of one batch.
__global__ void colsum_kernel(const float* __restrict__ feat, float* __restrict__ partial) {
    int blk = blockIdx.x;            // 0..511
    int b = blk >> 6, chunk = blk & 63;
    const float* base = feat + (size_t)b * (L * D) + (size_t)chunk * 16 * D;
    int t = threadIdx.x;             // 256
    float s0 = 0.f, s1 = 0.f;
    for (int l = 0; l < 16; ++l) {
        s0 += base[l * D + t];
        s1 += base[l * D + t + 256];
    }
    float* dst = partial + (size_t)blk * D;
    dst[t] = s0;
    dst[t + 256] = s1;
}

// ---------------- kernel 2: MLP head -> alpha/beta --------------------------
// grid: B blocks, 128 threads.
__global__ void head_kernel(const float* __restrict__ partial,
                            const float* __restrict__ W1, const float* __restrict__ b1,
                            const float* __restrict__ ln_g, const float* __restrict__ ln_b,
                            const float* __restrict__ W2, const float* __restrict__ b2,
                            float* __restrict__ ab, float* __restrict__ out_tail) {
    const int b = blockIdx.x;
    const int j = threadIdx.x;   // 0..127
    __shared__ float fm[D];
    __shared__ float red[DH];
    for (int d = j; d < D; d += DH) {
        float s = 0.f;
        const float* p = partial + (size_t)b * 64 * D + d;
        for (int c = 0; c < 64; ++c) s += p[c * D];
        fm[d] = s * (1.0f / (float)L);
    }
    __syncthreads();
    float h = b1[j];
    const vf4* fm4 = (const vf4*)fm;
    #pragma unroll 8
    for (int d4 = 0; d4 < D / 4; ++d4) {
        vf4 f = fm4[d4];
        h = fmaf(f.x, W1[(4 * d4 + 0) * DH + j], h);
        h = fmaf(f.y, W1[(4 * d4 + 1) * DH + j], h);
        h = fmaf(f.z, W1[(4 * d4 + 2) * DH + j], h);
        h = fmaf(f.w, W1[(4 * d4 + 3) * DH + j], h);
    }

    // mean
    red[j] = h; __syncthreads();
    for (int s = 64; s > 0; s >>= 1) { if (j < s) red[j] += red[j + s]; __syncthreads(); }
    float mu = red[0] * (1.f / (float)DH);
    __syncthreads();
    // var
    float hc = h - mu;
    red[j] = hc * hc; __syncthreads();
    for (int s = 64; s > 0; s >>= 1) { if (j < s) red[j] += red[j + s]; __syncthreads(); }
    float var = red[0] * (1.f / (float)DH);
    __syncthreads();

    float hn = hc * rsqrtf(var + 1e-5f) * ln_g[j] + ln_b[j];
    hn = fmaxf(hn, 0.f);

    red[j] = hn * W2[j * 2 + 0]; __syncthreads();
    for (int s = 64; s > 0; s >>= 1) { if (j < s) red[j] += red[j + s]; __syncthreads(); }
    float p0 = red[0];
    __syncthreads();
    red[j] = hn * W2[j * 2 + 1]; __syncthreads();
    for (int s = 64; s > 0; s >>= 1) { if (j < s) red[j] += red[j + s]; __syncthreads(); }
    float p1 = red[0];

    if (j == 0) {
        float a  = 0.00015f / (1.f + expf(-(p0 + b2[0])));
        float be = 0.00015f / (1.f + expf(-(p1 + b2[1])));
        ab[b] = a; ab[8 + b] = be;
        out_tail[b] = a; out_tail[8 + b] = be;
    }
}

// ---------------- kernel 3: horizontal 21-tap blur of mask ------------------
// grid: B*H blocks (one image row each), 256 threads.
__global__ void hblur_kernel(const float* __restrict__ mask, float* __restrict__ hmask,
                             BlurW kw) {
    int row = blockIdx.x;            // 0 .. B*H-1
    const float* src = mask + (size_t)row * W;
    __shared__ float srow[W + 24];   // data at [12 .. 12+W-1], zero halo 10 each side
    int t = threadIdx.x;             // 256
    if (t < 10) { srow[2 + t] = 0.f; srow[12 + W + t] = 0.f; }
    vf4 v = ((const vf4*)src)[t];
    ((vf4*)(srow + 12))[t] = v;
    __syncthreads();
    float* dst = hmask + (size_t)row * W;
    #pragma unroll
    for (int i = 0; i < 4; ++i) {
        int x = t + 256 * i;
        float acc = 0.f;
        #pragma unroll
        for (int k = 0; k < 21; ++k) acc = fmaf(kw.w[k], srow[x + 2 + k], acc);
        dst[x] = acc;
    }
}

// ---------------- kernel 4: vertical blur + elementwise synth ---------------
// grid: B*(H/TH) blocks; 256 threads = one float4 column group each.
// Register sliding window over 21 hmask rows; all indices compile-time.
__global__ __launch_bounds__(256) void final_kernel(
        const float* __restrict__ x_bg, const float* __restrict__ noise,
        const float* __restrict__ hmask, const float* __restrict__ ab,
        float* __restrict__ out, BlurW kw) {
    int blk = blockIdx.x;
    int b = blk >> 6;                // H/TH = 64 strips per batch
    int s = blk & 63;
    int h0 = s * TH;
    int t = threadIdx.x;             // 0..255

    const vf4* hm4 = (const vf4*)hmask + (size_t)b * H * (W / 4) + t;
    const vf4 zero4 = {0.f, 0.f, 0.f, 0.f};

    vf4 win[21];
    #pragma unroll
    for (int k = 0; k < 21; ++k) {
        int hy = h0 - 10 + k;
        win[k] = (hy >= 0 && hy < H) ? hm4[(size_t)hy * (W / 4)] : zero4;
    }

    float alpha = ab[b], beta = ab[8 + b];
    const vf4* x4 = (const vf4*)x_bg;
    const vf4* n4 = (const vf4*)noise;
    vf4* o4 = (vf4*)out;

    #pragma unroll
    for (int r = 0; r < TH; ++r) {
        vf4 ms = zero4;
        #pragma unroll
        for (int k = 0; k < 21; ++k) {
            float wk = kw.w[k];
            vf4 v = win[(r + k) % 21];       // static after unroll
            ms.x = fmaf(wk, v.x, ms.x);
            ms.y = fmaf(wk, v.y, ms.y);
            ms.z = fmaf(wk, v.z, ms.z);
            ms.w = fmaf(wk, v.w, ms.w);
        }
        int h = h0 + r;
        #pragma unroll
        for (int c = 0; c < C; ++c) {
            size_t idx = (((size_t)(b * C + c) * H) + h) * (W / 4) + t;
            vf4 x = __builtin_nontemporal_load(x4 + idx);
            vf4 nz = __builtin_nontemporal_load(n4 + idx);
            vf4 o;
            {
                float sg = sqrtf(fmaxf(fmaf(alpha, x.x, beta), 1e-7f));
                o.x = fmaf(1.5f * nz.x * sg, ms.x, x.x);
            }
            {
                float sg = sqrtf(fmaxf(fmaf(alpha, x.y, beta), 1e-7f));
                o.y = fmaf(1.5f * nz.y * sg, ms.y, x.y);
            }
            {
                float sg = sqrtf(fmaxf(fmaf(alpha, x.z, beta), 1e-7f));
                o.z = fmaf(1.5f * nz.z * sg, ms.z, x.z);
            }
            {
                float sg = sqrtf(fmaxf(fmaf(alpha, x.w, beta), 1e-7f));
                o.w = fmaf(1.5f * nz.w * sg, ms.w, x.w);
            }
            __builtin_nontemporal_store(o, o4 + idx);
        }
        if (r < TH - 1) {
            int hy = h0 + r + 11;
            win[r % 21] = (hy < H) ? hm4[(size_t)hy * (W / 4)] : zero4;
        }
    }
}

extern "C" void kernel_launch(void* const* d_in, const int* in_sizes, int n_in,
                              void* d_out, int out_size, void* d_ws, size_t ws_size,
                              hipStream_t stream) {
    const float* x_bg = (const float*)d_in[0];
    const float* feat = (const float*)d_in[1];
    const float* mask = (const float*)d_in[2];
    const float* noise = (const float*)d_in[3];
    const float* W1 = (const float*)d_in[4];
    const float* b1 = (const float*)d_in[5];
    const float* ln_g = (const float*)d_in[6];
    const float* ln_b = (const float*)d_in[7];
    const float* W2 = (const float*)d_in[8];
    const float* b2 = (const float*)d_in[9];
    float* out = (float*)d_out;

    // ws layout (floats): [0, 262144) partial colsums | [262144, +16) ab | hmask
    float* ws_f = (float*)d_ws;
    float* partial = ws_f;                       // B*64*D = 262144 floats
    float* ab = ws_f + 262144;                   // 16 floats
    float* hmask = ws_f + 262144 + 64;           // B*H*W floats (16B-aligned offset)

    BlurW kw;
    {
        double g[21], s = 0.0;
        for (int i = 0; i < 21; ++i) { double x = (double)(i - 10); g[i] = exp(-x * x / 50.0); s += g[i]; }
        for (int i = 0; i < 21; ++i) kw.w[i] = (float)(g[i] / s);
    }

    colsum_kernel<<<B * 64, 256, 0, stream>>>(feat, partial);
    head_kernel<<<B, 128, 0, stream>>>(partial, W1, b1, ln_g, ln_b, W2, b2,
                                       ab, out + NOISY_ELEMS);
    hblur_kernel<<<B * H, 256, 0, stream>>>(mask, hmask, kw);
    final_kernel<<<B * (H / TH), 256, 0, stream>>>(x_bg, noise, hmask, ab, out, kw);
}